// Round 14
// baseline (507.886 us; speedup 1.0000x reference)
//
#include <hip/hip_runtime.h>
#include <math.h>

// ---------------------------------------------------------------------------
// Swin-3D cross-attention block. Round 20:
//  - k_conv v3: MFMA conv. R13 counters: 93.5us, VALU 68%, MfmaUtil 0 ->
//    matmul-shaped work on the vector ALU. Now out[p][oc] = sum_kk
//    X[p+dkk][:] @ Wkk via 27 taps x 3 mfma_16x16x32 (one wave = 16 points,
//    single 16x16 C tile, oc<3 used). Boundary taps select a zeroed global
//    page (branch-free). Weights re-laid wcvT[27][16][96] bf16 in k_prep.
//    2 interleaved accumulators; no LDS.
//  - k_ln v3 validated R13 (out of top-5). k_mlp v8 / k_attn v2 retained.
// Token order = window-partitioned:
//   win = ((b*8 + d/5)*8 + h/6)*8 + w/5 ; t = ((d%5)*6 + h%6)*5 + w%5
// ---------------------------------------------------------------------------

static constexpr int NTOK = 153600;
static constexpr float SCALE = 0.10206207261596575f; // 96^-0.5

typedef __bf16 bf16_t;
typedef __bf16 bf16x8 __attribute__((ext_vector_type(8)));
typedef float f32x4 __attribute__((ext_vector_type(4)));

__device__ __forceinline__ int tok_index(int b, int d, int h, int w) {
    int d0 = d / 5, wd = d % 5;
    int h0 = h / 6, wh = h % 6;
    int w0 = w / 5, ww = w % 5;
    int win = ((b * 8 + d0) * 8 + h0) * 8 + w0;
    return win * 150 + (wd * 6 + wh) * 5 + ww;
}

__device__ __forceinline__ float gelu_f(float u) {
    float u2 = u * u;
    float arg = u * fmaf(0.0713549f, u2, 1.5957691f);
    float e = __expf(arg);
    float r = __builtin_amdgcn_rcpf(e + 1.f);
    return fmaf(-u, r, u);
}

// ---------------------------------------------------------------------------
// K0: weight convert/transpose bf16 [n][k]; fp32 bias matrix [160][160];
// conv weights re-laid to wcvT[kk][oc16][ci] bf16 (oc>=3 zeroed) + 96-elem
// zero page for boundary taps. grid = 162, 256 threads.
// ---------------------------------------------------------------------------
__global__ __launch_bounds__(256) void k_prep_weights(
    const float* __restrict__ wq, const float* __restrict__ wkv,
    const float* __restrict__ w1, const float* __restrict__ w2,
    const float* __restrict__ wproj, const float* __restrict__ relb,
    const float* __restrict__ cw,
    bf16_t* wqT, bf16_t* wkvT, bf16_t* w1T, bf16_t* w2T, bf16_t* wpjT,
    float* bias_mat, bf16_t* wcvT, bf16_t* zpad)
{
    int i = blockIdx.x * 256 + threadIdx.x;
    if (i < 9216)  wqT[i]  = (bf16_t)wq[(i % 96) * 96 + i / 96];
    if (i < 18432) wkvT[i] = (bf16_t)wkv[(i % 96) * 192 + i / 96];
    if (i < 36864) w1T[i]  = (bf16_t)w1[(i % 96) * 384 + i / 96];
    if (i < 36864) w2T[i]  = (bf16_t)w2[(i % 384) * 96 + i / 384];
    if (i < 9216)  wpjT[i] = (bf16_t)wproj[(i % 96) * 96 + i / 96];
    if (i < 25600) {
        int row = i / 160, col = i % 160;
        float v;
        if (col >= 150) v = -1e30f;
        else if (row >= 150) v = 0.f;
        else {
            int wd1 = row / 30, rh1 = row % 30, wh1 = rh1 / 5, ww1 = rh1 % 5;
            int wd2 = col / 30, rh2 = col % 30, wh2 = rh2 / 5, ww2 = rh2 % 5;
            int idx = (wd1 - wd2 + 4) * 99 + (wh1 - wh2 + 5) * 9 + (ww1 - ww2 + 4);
            v = relb[idx];
        }
        bias_mat[i] = v;
    }
    if (i < 41472) {   // wcvT[kk][oc16][ci], oc>=3 -> 0
        int kk = i / 1536, rem2 = i % 1536;
        int oc = rem2 / 96, ci = rem2 % 96;
        wcvT[i] = (bf16_t)(oc < 3 ? cw[oc * 2592 + ci * 27 + kk] : 0.f);
    }
    if (i < 96) zpad[i] = (bf16_t)0.f;
}

// ---------------------------------------------------------------------------
// K1 v3: transpose->token order + LayerNorm + fp32 Im shortcut.
// One block per (b, d, h-pair): rows h0,h0+1 are CONTIGUOUS in memory ->
// float4 loads over 320B runs. Stores vectorized: bf16x8 (uint4) + 2x float4.
// grid = 1920, 256 threads, 2 passes (Im->xln/x2s, If->yln).
// ---------------------------------------------------------------------------
__global__ __launch_bounds__(256) void k_ln_transpose(
    const float* __restrict__ Im, const float* __restrict__ If,
    const float* __restrict__ g1q, const float* __restrict__ b1q,
    const float* __restrict__ g1k, const float* __restrict__ b1k,
    bf16_t* __restrict__ xln, bf16_t* __restrict__ yln,
    float* __restrict__ x2s)
{
    __shared__ float tile[80 * 97];          // 31040 B
    __shared__ float red_s[80][3], red2_s[80][3];
    __shared__ float mean_s[80], rstd_s[80];
    int blk = blockIdx.x;                    // 2 * 40 * 24
    int b = blk / (40 * 24);
    int rem = blk % (40 * 24);
    int d = rem / 24, hp = rem % 24;
    int h0 = hp * 2;
    int tid = threadIdx.x;

    for (int pass = 0; pass < 2; ++pass) {
        const float* src = pass ? If : Im;
        const float* gg = pass ? g1k : g1q;
        const float* bb = pass ? b1k : b1q;
        bf16_t* dst = pass ? yln : xln;

        // ---- load: float4 over the 80-float contiguous (h0,h0+1) span ----
        for (int i = tid; i < 1920; i += 256) {
            int c = i / 20, q = i % 20;
            float4 v = *(const float4*)(src + (size_t)(b * 96 + c) * 76800
                                        + d * 1920 + h0 * 40 + q * 4);
            int w0 = q * 4;
            tile[(w0 + 0) * 97 + c] = v.x;
            tile[(w0 + 1) * 97 + c] = v.y;
            tile[(w0 + 2) * 97 + c] = v.z;
            tile[(w0 + 3) * 97 + c] = v.w;
        }
        __syncthreads();
        // ---- stats: 240 threads, (token w6, third j) 32-chan partials ----
        if (tid < 240) {
            int w6 = tid / 3, j = tid % 3;
            const float* tp = tile + w6 * 97 + j * 32;
            float s = 0.f, s2 = 0.f;
#pragma unroll
            for (int c = 0; c < 32; ++c) { float v = tp[c]; s += v; s2 += v * v; }
            red_s[w6][j] = s;
            red2_s[w6][j] = s2;
        }
        __syncthreads();
        if (tid < 80) {
            float s = red_s[tid][0] + red_s[tid][1] + red_s[tid][2];
            float s2 = red2_s[tid][0] + red2_s[tid][1] + red2_s[tid][2];
            float m = s * (1.f / 96.f);
            float var = s2 * (1.f / 96.f) - m * m;
            mean_s[tid] = m;
            rstd_s[tid] = rsqrtf(var + 1e-5f);
        }
        __syncthreads();
        // ---- store: (token w, 8-chan group c8); vectorized 16B stores ----
        for (int i = tid; i < 960; i += 256) {
            int w = i / 12, c8 = i % 12;
            int hh = h0 + (w >= 40), ww = w - (w >= 40) * 40;
            int tok = tok_index(b, d, hh, ww);
            float m = mean_s[w], rs = rstd_s[w];
            const float4* ggv = (const float4*)(gg + c8 * 8);
            const float4* bbv = (const float4*)(bb + c8 * 8);
            float4 g0 = ggv[0], g1 = ggv[1];
            float4 b0 = bbv[0], b1v = bbv[1];
            const float* tp = tile + w * 97 + c8 * 8;
            float x0 = tp[0], x1 = tp[1], x2v = tp[2], x3 = tp[3];
            float x4 = tp[4], x5 = tp[5], x6 = tp[6], x7 = tp[7];
            bf16x8 tb;
            tb[0] = (bf16_t)((x0 - m) * rs * g0.x + b0.x);
            tb[1] = (bf16_t)((x1 - m) * rs * g0.y + b0.y);
            tb[2] = (bf16_t)((x2v - m) * rs * g0.z + b0.z);
            tb[3] = (bf16_t)((x3 - m) * rs * g0.w + b0.w);
            tb[4] = (bf16_t)((x4 - m) * rs * g1.x + b1v.x);
            tb[5] = (bf16_t)((x5 - m) * rs * g1.y + b1v.y);
            tb[6] = (bf16_t)((x6 - m) * rs * g1.z + b1v.z);
            tb[7] = (bf16_t)((x7 - m) * rs * g1.w + b1v.w);
            *(bf16x8*)(dst + (size_t)tok * 96 + c8 * 8) = tb;
            if (pass == 0) {
                float* xp = x2s + (size_t)tok * 96 + c8 * 8;
                *(float4*)(xp) = make_float4(x0, x1, x2v, x3);
                *(float4*)(xp + 4) = make_float4(x4, x5, x6, x7);
            }
        }
        __syncthreads();
    }
}

// ---------------------------------------------------------------------------
// K2: MFMA projection. WT is [N][96] bf16, staged once per block into LDS
// ([N][104] padded) so B-frags come from LDS, not per-MFMA global loads.
// N=96 -> qb only. N=192 -> n<96 writes kb [t][c]; n>=96 writes vT.
// grid = 2400 (64 tokens/block), 256 threads = 4 waves.
// dynamic LDS = (64*104 + N*104)*2 B.
// ---------------------------------------------------------------------------
__global__ __launch_bounds__(256) void k_proj_mfma(
    const bf16_t* __restrict__ X, const bf16_t* __restrict__ WT,
    const float* __restrict__ bias, int N,
    bf16_t* __restrict__ outA, bf16_t* __restrict__ vT)
{
    extern __shared__ bf16_t sm[];
    bf16_t* xs  = sm;             // [64][104]
    bf16_t* wsh = sm + 64 * 104;  // [N][104]
    int tid = threadIdx.x;
    int t0 = blockIdx.x * 64;

    const uint4* xg = (const uint4*)(X + (size_t)t0 * 96);
    uint4* xsv = (uint4*)xs;
    for (int i = tid; i < 768; i += 256) {
        int row = i / 12, c16 = i % 12;
        xsv[row * 13 + c16] = xg[i];
    }
    const uint4* wg = (const uint4*)WT;
    uint4* wsv = (uint4*)wsh;
    for (int i = tid; i < N * 12; i += 256) {
        int row = i / 12, c16 = i % 12;
        wsv[row * 13 + c16] = wg[i];
    }
    __syncthreads();

    int w = tid >> 6, l = tid & 63;
    int lm = l & 15, lk = (l >> 4) * 8;
    int m0 = w * 16;
    bf16x8 a[3];
#pragma unroll
    for (int kk = 0; kk < 3; ++kk)
        a[kk] = *(const bf16x8*)(xs + (m0 + lm) * 104 + kk * 32 + lk);

    int trow[4], twin[4], tm[4];
#pragma unroll
    for (int r = 0; r < 4; ++r) {
        int t = t0 + m0 + (l >> 4) * 4 + r;
        trow[r] = t; twin[r] = t / 150; tm[r] = t - twin[r] * 150;
    }

    int ntiles = N >> 4;
    for (int ti = 0; ti < ntiles; ++ti) {
        int n0 = ti * 16;
        f32x4 c = {0.f, 0.f, 0.f, 0.f};
        const bf16_t* wp = wsh + (size_t)(n0 + lm) * 104 + lk;
        c = __builtin_amdgcn_mfma_f32_16x16x32_bf16(a[0], *(const bf16x8*)(wp), c, 0, 0, 0);
        c = __builtin_amdgcn_mfma_f32_16x16x32_bf16(a[1], *(const bf16x8*)(wp + 32), c, 0, 0, 0);
        c = __builtin_amdgcn_mfma_f32_16x16x32_bf16(a[2], *(const bf16x8*)(wp + 64), c, 0, 0, 0);
        int n = n0 + lm;
        float bs = bias[n];
        if (n < 96) {
#pragma unroll
            for (int r = 0; r < 4; ++r)
                outA[(size_t)trow[r] * 96 + n] = (bf16_t)(c[r] + bs);
        } else {
            int cc = n - 96;
#pragma unroll
            for (int r = 0; r < 4; ++r)
                vT[((size_t)twin[r] * 96 + cc) * 160 + tm[r]] = (bf16_t)(c[r] + bs);
        }
    }
}

// ---------------------------------------------------------------------------
// K34 v2: waveized MFMA attention. One wave = one (window, row-tile) task,
// 10240 tasks, 4 waves/block, grid 2560. No barriers, no K staging (K is
// L1/L2-hot: 28.8 KB/window shared by its 10 waves). P/O transpose through
// wave-private LDS scratch [16][164]. K rows >=150 clamp-loaded (masked by
// bias -1e30). Output: aob[t][c] = O @ wprojT + bproj (bf16), no x2 RMW.
// ---------------------------------------------------------------------------
__global__ __launch_bounds__(256, 4) void k_attn_mfma(
    const bf16_t* __restrict__ qb, const bf16_t* __restrict__ kb,
    const bf16_t* __restrict__ vT, const bf16_t* __restrict__ wpjT,
    const float* __restrict__ bias_mat, const float* __restrict__ bproj,
    bf16_t* __restrict__ aob)
{
    __shared__ __align__(16) bf16_t pls_all[4 * 16 * 164]; // 20992 B
    int tid = threadIdx.x;
    int wv = tid >> 6, l = tid & 63;
    int task = blockIdx.x * 4 + wv;
    int win = task / 10, ti = task - win * 10;
    int lm = l & 15, lq = l >> 4, lk8 = lq * 8;
    size_t wbase = (size_t)win * 150 * 96;
    size_t vbase = (size_t)win * 96 * 160;
    bf16_t* pls = pls_all + wv * 16 * 164;
    int r0 = ti * 16;

    // ---- Q A-frags from global (rows >=150 read harmless garbage; masked) --
    bf16x8 aq[3];
#pragma unroll
    for (int kk = 0; kk < 3; ++kk)
        aq[kk] = *(const bf16x8*)(qb + wbase + (size_t)(r0 + lm) * 96 + kk * 32 + lk8);

    // ---- S = Q K^T (K B-frags from global, L1-hot; clamp rows >=150) ----
    f32x4 s[10];
#pragma unroll
    for (int nt = 0; nt < 10; ++nt) {
        int krow = nt * 16 + lm;
        if (krow > 149) krow = 149;   // finite duplicate, masked by bias
        f32x4 acc = {0.f, 0.f, 0.f, 0.f};
        const bf16_t* kp = kb + wbase + (size_t)krow * 96 + lk8;
        acc = __builtin_amdgcn_mfma_f32_16x16x32_bf16(aq[0], *(const bf16x8*)(kp), acc, 0, 0, 0);
        acc = __builtin_amdgcn_mfma_f32_16x16x32_bf16(aq[1], *(const bf16x8*)(kp + 32), acc, 0, 0, 0);
        acc = __builtin_amdgcn_mfma_f32_16x16x32_bf16(aq[2], *(const bf16x8*)(kp + 64), acc, 0, 0, 0);
        s[nt] = acc;
    }

    // ---- softmax (bias+mask folded into bias_mat) ----
#pragma unroll
    for (int r = 0; r < 4; ++r) {
        int grow = r0 + lq * 4 + r;
        float rowmax = -3.0e38f;
#pragma unroll
        for (int nt = 0; nt < 10; ++nt) {
            float bv = bias_mat[grow * 160 + nt * 16 + lm];
            float v = fmaf(s[nt][r], SCALE, bv);
            s[nt][r] = v;
            rowmax = fmaxf(rowmax, v);
        }
        rowmax = fmaxf(rowmax, __shfl_xor(rowmax, 1));
        rowmax = fmaxf(rowmax, __shfl_xor(rowmax, 2));
        rowmax = fmaxf(rowmax, __shfl_xor(rowmax, 4));
        rowmax = fmaxf(rowmax, __shfl_xor(rowmax, 8));
        float ssum = 0.f;
#pragma unroll
        for (int nt = 0; nt < 10; ++nt) {
            float e = __expf(s[nt][r] - rowmax);
            s[nt][r] = e;
            ssum += e;
        }
        ssum += __shfl_xor(ssum, 1);
        ssum += __shfl_xor(ssum, 2);
        ssum += __shfl_xor(ssum, 4);
        ssum += __shfl_xor(ssum, 8);
        float inv = 1.f / ssum;
        int lrow = lq * 4 + r;
#pragma unroll
        for (int nt = 0; nt < 10; ++nt)
            pls[lrow * 164 + nt * 16 + lm] = (bf16_t)(s[nt][r] * inv);
    }
    // wave-private LDS: no barrier needed (lgkmcnt orders within wave)

    // ---- O = P @ V (P A-frags from LDS, V B-frags from global, L2-hot) ----
    f32x4 o[6];
#pragma unroll
    for (int ct = 0; ct < 6; ++ct) o[ct] = (f32x4){0.f, 0.f, 0.f, 0.f};
#pragma unroll
    for (int kf = 0; kf < 5; ++kf) {
        bf16x8 ap = *(const bf16x8*)(pls + lm * 164 + kf * 32 + lk8);
#pragma unroll
        for (int ct = 0; ct < 6; ++ct) {
            const bf16_t* vp = vT + vbase + (size_t)(ct * 16 + lm) * 160 + kf * 32 + lk8;
            o[ct] = __builtin_amdgcn_mfma_f32_16x16x32_bf16(ap, *(const bf16x8*)(vp), o[ct], 0, 0, 0);
        }
    }

    // ---- O -> LDS (A-layout staging), reuse pls as [16][104] ----
#pragma unroll
    for (int ct = 0; ct < 6; ++ct)
#pragma unroll
        for (int r = 0; r < 4; ++r)
            pls[(lq * 4 + r) * 104 + ct * 16 + lm] = (bf16_t)o[ct][r];

    // ---- aob = O @ wprojT + bproj (bf16) ----
    bf16x8 ao[3];
#pragma unroll
    for (int kk = 0; kk < 3; ++kk)
        ao[kk] = *(const bf16x8*)(pls + lm * 104 + kk * 32 + lk8);
    f32x4 pj[6];
#pragma unroll
    for (int ct = 0; ct < 6; ++ct) {
        f32x4 acc = {0.f, 0.f, 0.f, 0.f};
        const bf16_t* wp = wpjT + (size_t)(ct * 16 + lm) * 96 + lk8;
        acc = __builtin_amdgcn_mfma_f32_16x16x32_bf16(ao[0], *(const bf16x8*)(wp), acc, 0, 0, 0);
        acc = __builtin_amdgcn_mfma_f32_16x16x32_bf16(ao[1], *(const bf16x8*)(wp + 32), acc, 0, 0, 0);
        acc = __builtin_amdgcn_mfma_f32_16x16x32_bf16(ao[2], *(const bf16x8*)(wp + 64), acc, 0, 0, 0);
        pj[ct] = acc;
    }
#pragma unroll
    for (int r = 0; r < 4; ++r) {
        int gr = r0 + lq * 4 + r;
        if (gr < 150) {
            size_t t = (size_t)win * 150 + gr;
#pragma unroll
            for (int ct = 0; ct < 6; ++ct) {
                int c = ct * 16 + lm;
                aob[t * 96 + c] = (bf16_t)(pj[ct][r] + bproj[c]);
            }
        }
    }
}

// ---------------------------------------------------------------------------
// K5: MFMA MLP v8. Weight chunks staged cooperatively in LDS (k_proj
// pattern). xs/h alias retained (wave-private). LDS 46592 B -> 3 blk/CU.
// grid = 1200 (128 tokens), 256 threads = 4 waves, 32 tokens/wave.
// ---------------------------------------------------------------------------
__global__ __launch_bounds__(256, 3) void k_mlp_mfma(
    const float* __restrict__ x2,
    const bf16_t* __restrict__ aob,
    const float* __restrict__ g2, const float* __restrict__ b2,
    const bf16_t* __restrict__ w1T, const float* __restrict__ b1,
    const bf16_t* __restrict__ w2T, const float* __restrict__ b2v,
    bf16_t* __restrict__ xc)
{
    __shared__ __align__(16) bf16_t xs[128 * 104];   // 26624 B (xs, then h)
    __shared__ __align__(16) bf16_t wsm[96 * 104];   // 19968 B (weight chunk)

    int tid = threadIdx.x;
    int t0 = blockIdx.x * 128;

    // ---- register LayerNorm: thread = (token t, half p); x2 = x2s + aob ----
    {
        int t = tid >> 1, p = tid & 1;
        float xr[48];
        const float4* xg = (const float4*)(x2 + (size_t)(t0 + t) * 96 + p * 48);
        const bf16x8* ag = (const bf16x8*)(aob + (size_t)(t0 + t) * 96 + p * 48);
#pragma unroll
        for (int j4 = 0; j4 < 12; ++j4) {
            float4 v = xg[j4];
            xr[j4 * 4 + 0] = v.x; xr[j4 * 4 + 1] = v.y;
            xr[j4 * 4 + 2] = v.z; xr[j4 * 4 + 3] = v.w;
        }
#pragma unroll
        for (int j8 = 0; j8 < 6; ++j8) {
            bf16x8 av = ag[j8];
#pragma unroll
            for (int e = 0; e < 8; ++e)
                xr[j8 * 8 + e] += (float)av[e];
        }
        float s = 0.f, s2 = 0.f;
#pragma unroll
        for (int j = 0; j < 48; ++j) { s += xr[j]; s2 += xr[j] * xr[j]; }
        s += __shfl_xor(s, 1);
        s2 += __shfl_xor(s2, 1);
        float m = s * (1.f / 96.f);
        float var = s2 * (1.f / 96.f) - m * m;
        float rstd = rsqrtf(var + 1e-5f);

        const float4* gg = (const float4*)(g2 + p * 48);
        const float4* bb = (const float4*)(b2 + p * 48);
        bf16_t tmp[48];
#pragma unroll
        for (int j4 = 0; j4 < 12; ++j4) {
            float4 g = gg[j4], bv = bb[j4];
            tmp[j4 * 4 + 0] = (bf16_t)((xr[j4 * 4 + 0] - m) * rstd * g.x + bv.x);
            tmp[j4 * 4 + 1] = (bf16_t)((xr[j4 * 4 + 1] - m) * rstd * g.y + bv.y);
            tmp[j4 * 4 + 2] = (bf16_t)((xr[j4 * 4 + 2] - m) * rstd * g.z + bv.z);
            tmp[j4 * 4 + 3] = (bf16_t)((xr[j4 * 4 + 3] - m) * rstd * g.w + bv.w);
        }
        uint4* dst = (uint4*)(xs + t * 104 + p * 48);   // 96B per half
        const uint4* src = (const uint4*)tmp;
#pragma unroll
        for (int j = 0; j < 6; ++j) dst[j] = src[j];
    }
    // NO barrier for xs: token rows [32w,32w+32) are written by wave w's own
    // tids; in-wave DS ordering suffices. Barriers below only guard wsm.

    int w = tid >> 6, l = tid & 63;
    int lm = l & 15, lq = l >> 4, lk = lq * 8;
    int m0 = w * 32;
    bf16_t* hw = xs + w * 32 * 104;   // ALIAS: xs rows dead after a-frag load

    bf16x8 a[2][3];
#pragma unroll
    for (int mt = 0; mt < 2; ++mt)
#pragma unroll
        for (int kk = 0; kk < 3; ++kk)
            a[mt][kk] = *(const bf16x8*)(xs + (m0 + mt * 16 + lm) * 104 + kk * 32 + lk);

    f32x4 acc2[2][6];
#pragma unroll
    for (int mt = 0; mt < 2; ++mt)
#pragma unroll
        for (int i = 0; i < 6; ++i) acc2[mt][i] = (f32x4){0.f, 0.f, 0.f, 0.f};

    // cooperative stage of a [96][96] weight chunk into wsm[96][104]
    auto stage_w = [&](const bf16_t* src, int srcStride) {
        uint4* wv = (uint4*)wsm;
        for (int i = tid; i < 1152; i += 256) {
            int row = i / 12, c = i - row * 12;
            wv[row * 13 + c] = *(const uint4*)(src + (size_t)row * srcStride + c * 8);
        }
    };

#pragma unroll
    for (int cc = 0; cc < 4; ++cc) {
        // ---- stage w1 chunk; all waves consume from LDS ----
        stage_w(w1T + (size_t)cc * 96 * 96, 96);
        __syncthreads();
        // ---- stage1: h = gelu(x @ w1_cc + b1) ----
#pragma unroll
        for (int ti = 0; ti < 6; ++ti) {
            int n = cc * 96 + ti * 16 + lm;
            const bf16_t* wp = wsm + (size_t)(ti * 16 + lm) * 104 + lk;
            bf16x8 w0 = *(const bf16x8*)(wp);
            bf16x8 w1v = *(const bf16x8*)(wp + 32);
            bf16x8 w2v = *(const bf16x8*)(wp + 64);
            float bs = b1[n];
#pragma unroll
            for (int mt = 0; mt < 2; ++mt) {
                f32x4 c1 = {0.f, 0.f, 0.f, 0.f};
                c1 = __builtin_amdgcn_mfma_f32_16x16x32_bf16(a[mt][0], w0, c1, 0, 0, 0);
                c1 = __builtin_amdgcn_mfma_f32_16x16x32_bf16(a[mt][1], w1v, c1, 0, 0, 0);
                c1 = __builtin_amdgcn_mfma_f32_16x16x32_bf16(a[mt][2], w2v, c1, 0, 0, 0);
#pragma unroll
                for (int r = 0; r < 4; ++r)
                    hw[(mt * 16 + lq * 4 + r) * 104 + ti * 16 + lm] =
                        (bf16_t)gelu_f(c1[r] + bs);
            }
        }
        __syncthreads();   // all wsm (w1) reads done before overwrite

        // ---- stage w2 chunk; consume from LDS ----
        stage_w(w2T + (size_t)cc * 96, 384);
        __syncthreads();
        // ---- stage2: acc2 += h_cc @ w2_cc ----
        bf16x8 ha[2][3];
#pragma unroll
        for (int mt = 0; mt < 2; ++mt)
#pragma unroll
            for (int kk = 0; kk < 3; ++kk)
                ha[mt][kk] = *(const bf16x8*)(hw + (mt * 16 + lm) * 104 + kk * 32 + lk);
#pragma unroll
        for (int ti = 0; ti < 6; ++ti) {
            const bf16_t* wp = wsm + (size_t)(ti * 16 + lm) * 104 + lk;
            bf16x8 v0 = *(const bf16x8*)(wp);
            bf16x8 v1 = *(const bf16x8*)(wp + 32);
            bf16x8 v2 = *(const bf16x8*)(wp + 64);
#pragma unroll
            for (int mt = 0; mt < 2; ++mt) {
                acc2[mt][ti] = __builtin_amdgcn_mfma_f32_16x16x32_bf16(ha[mt][0], v0, acc2[mt][ti], 0, 0, 0);
                acc2[mt][ti] = __builtin_amdgcn_mfma_f32_16x16x32_bf16(ha[mt][1], v1, acc2[mt][ti], 0, 0, 0);
                acc2[mt][ti] = __builtin_amdgcn_mfma_f32_16x16x32_bf16(ha[mt][2], v2, acc2[mt][ti], 0, 0, 0);
            }
        }
        if (cc < 3) __syncthreads();   // wsm (w2) reads done before next cc
    }

    // epilogue: residual (x2s + aob) + bias; write bf16 in spatial order
#pragma unroll
    for (int mt = 0; mt < 2; ++mt) {
        int srow[4];
#pragma unroll
        for (int r = 0; r < 4; ++r) {
            int t = t0 + m0 + mt * 16 + lq * 4 + r;
            int win = t / 150, nn = t - win * 150;
            int b = win >> 9, d0 = (win >> 6) & 7, h0 = (win >> 3) & 7, w0 = win & 7;
            int wd = nn / 30, rem = nn % 30, wh = rem / 5, ww = rem % 5;
            srow[r] = ((b * 40 + d0 * 5 + wd) * 48 + h0 * 6 + wh) * 40 + w0 * 5 + ww;
        }
#pragma unroll
        for (int ti = 0; ti < 6; ++ti) {
            int n = ti * 16 + lm;
            float bs = b2v[n];
#pragma unroll
            for (int r = 0; r < 4; ++r) {
                int t = t0 + m0 + mt * 16 + lq * 4 + r;
                size_t o = (size_t)t * 96 + n;
                float base = x2[o] + (float)aob[o];
                xc[(size_t)srow[r] * 96 + n] = (bf16_t)(base + acc2[mt][ti][r] + bs);
            }
        }
    }
}

// ---------------------------------------------------------------------------
// K6 v3: MFMA 3x3x3 conv (96 -> 3). One wave = 16 points; C tile 16pt x 16oc
// (oc<3 used). 27 taps x 3 mfma_16x16x32_bf16 accumulate into 2 interleaved
// C accumulators. A-frags: per-lane shifted-point row pointers, OOB -> zpad.
// B-frags: wcvT[kk][16][96] bf16 (L1-hot, 83KB). No LDS.
// grid = 2400, 256 threads = 4 waves.
// ---------------------------------------------------------------------------
__global__ __launch_bounds__(256) void k_conv(
    const bf16_t* __restrict__ xc, const bf16_t* __restrict__ wcvT,
    const bf16_t* __restrict__ zpad,
    const float* __restrict__ cb, float* __restrict__ out)
{
    int tid = threadIdx.x;
    int wv = tid >> 6, l = tid & 63;
    int lm = l & 15, lq = l >> 4, lk8 = lq * 8;
    int p0 = blockIdx.x * 64 + wv * 16;
    int p = p0 + lm;                        // this lane's A-row point
    int b = p / 76800, rr = p % 76800;
    int d = rr / 1920, h = (rr / 40) % 48, w = rr % 40;

    f32x4 c0 = {0.f, 0.f, 0.f, 0.f};
    f32x4 c1v = {0.f, 0.f, 0.f, 0.f};

#pragma unroll
    for (int dd = 0; dd < 3; ++dd) {
        int d2 = d + dd - 1;
        bool okd = (unsigned)d2 < 40u;
#pragma unroll
        for (int hh = 0; hh < 3; ++hh) {
            int h2 = h + hh - 1;
            bool okh = (unsigned)h2 < 48u;
#pragma unroll
            for (int ww = 0; ww < 3; ++ww) {
                int w2 = w + ww - 1;
                bool ok = okd && okh && ((unsigned)w2 < 40u);
                int kk = (dd * 3 + hh) * 3 + ww;
                int src = ((b * 40 + d2) * 48 + h2) * 40 + w2;
                const bf16_t* pa = ok ? (xc + (size_t)src * 96) : zpad;
                const bf16_t* pb = wcvT + kk * 1536 + lm * 96;
                if (kk & 1) {
                    c1v = __builtin_amdgcn_mfma_f32_16x16x32_bf16(
                        *(const bf16x8*)(pa + lk8), *(const bf16x8*)(pb + lk8), c1v, 0, 0, 0);
                    c1v = __builtin_amdgcn_mfma_f32_16x16x32_bf16(
                        *(const bf16x8*)(pa + 32 + lk8), *(const bf16x8*)(pb + 32 + lk8), c1v, 0, 0, 0);
                    c1v = __builtin_amdgcn_mfma_f32_16x16x32_bf16(
                        *(const bf16x8*)(pa + 64 + lk8), *(const bf16x8*)(pb + 64 + lk8), c1v, 0, 0, 0);
                } else {
                    c0 = __builtin_amdgcn_mfma_f32_16x16x32_bf16(
                        *(const bf16x8*)(pa + lk8), *(const bf16x8*)(pb + lk8), c0, 0, 0, 0);
                    c0 = __builtin_amdgcn_mfma_f32_16x16x32_bf16(
                        *(const bf16x8*)(pa + 32 + lk8), *(const bf16x8*)(pb + 32 + lk8), c0, 0, 0, 0);
                    c0 = __builtin_amdgcn_mfma_f32_16x16x32_bf16(
                        *(const bf16x8*)(pa + 64 + lk8), *(const bf16x8*)(pb + 64 + lk8), c0, 0, 0, 0);
                }
            }
        }
    }

    // C layout: col = lm (oc), row = lq*4 + r (point p0+row)
    if (lm < 3) {
        float bsv = cb[lm];
#pragma unroll
        for (int r = 0; r < 4; ++r) {
            int pt = p0 + lq * 4 + r;
            int bb2 = pt / 76800, rp = pt % 76800;
            out[(size_t)(bb2 * 3 + lm) * 76800 + rp] = c0[r] + c1v[r] + bsv;
        }
    }
}

// ---------------------------------------------------------------------------
extern "C" void kernel_launch(void* const* d_in, const int* in_sizes, int n_in,
                              void* d_out, int out_size, void* d_ws, size_t ws_size,
                              hipStream_t stream)
{
    (void)in_sizes; (void)n_in; (void)out_size;

    const float* Im  = (const float*)d_in[0];
    const float* If  = (const float*)d_in[1];
    const float* g1q = (const float*)d_in[2];
    const float* b1q = (const float*)d_in[3];
    const float* g1k = (const float*)d_in[4];
    const float* b1k = (const float*)d_in[5];
    const float* wq  = (const float*)d_in[6];
    const float* bq  = (const float*)d_in[7];
    const float* wkv = (const float*)d_in[8];
    const float* bkv = (const float*)d_in[9];
    const float* wpj = (const float*)d_in[10];
    const float* bpj = (const float*)d_in[11];
    const float* rb  = (const float*)d_in[12];
    const float* g2  = (const float*)d_in[13];
    const float* b2  = (const float*)d_in[14];
    const float* w1  = (const float*)d_in[15];
    const float* b1  = (const float*)d_in[16];
    const float* w2  = (const float*)d_in[17];
    const float* b2v = (const float*)d_in[18];
    const float* cw  = (const float*)d_in[19];
    const float* cb  = (const float*)d_in[20];
    float* out = (float*)d_out;

    size_t U = (size_t)NTOK * 96;
    if (ws_size < 4 * U * sizeof(float)) return;
    float* ws = (float*)d_ws;
    bf16_t* xlnb = (bf16_t*)ws;                        // U bf16 (-> aob later)
    bf16_t* ylnb = (bf16_t*)(ws + U / 2);              // U bf16 (-> xc later)
    bf16_t* qb   = (bf16_t*)(ws + U);                  // U bf16
    bf16_t* kb   = (bf16_t*)(ws + 3 * U / 2);          // U bf16
    bf16_t* vT   = (bf16_t*)(ws + 2 * U);              // 1024*96*160 bf16
    float*  wtail = ws + 2 * U + (1024 * 96 * 160) / 2;
    bf16_t* wqT  = (bf16_t*)wtail;                     // 9216
    bf16_t* wkvT = wqT + 9216;                         // 18432
    bf16_t* w1T  = wkvT + 18432;                       // 36864
    bf16_t* w2T  = w1T + 36864;                        // 36864
    bf16_t* wpjT = w2T + 36864;                        // 9216
    float*  bias_mat = (float*)(wpjT + 9216 + 2);      // 25600 fp32
    bf16_t* wcvT = (bf16_t*)(bias_mat + 25600);        // 41472 bf16
    bf16_t* zpad = wcvT + 41472;                       // 96 bf16 zero page
    float*  x2f  = ws + 3 * U;                         // U fp32 (x2s shortcut)
    bf16_t* aob  = (bf16_t*)ws;                        // U bf16 (attn out)
    bf16_t* xc   = (bf16_t*)(ws + U / 2);              // U bf16, spatial order

    k_prep_weights<<<162, 256, 0, stream>>>(wq, wkv, w1, w2, wpj, rb, cw,
                                            wqT, wkvT, w1T, w2T, wpjT,
                                            bias_mat, wcvT, zpad);
    k_ln_transpose<<<1920, 256, 0, stream>>>(Im, If, g1q, b1q, g1k, b1k,
                                             xlnb, ylnb, x2f);
    size_t shm_q  = (size_t)(64 * 104 + 96 * 104) * sizeof(bf16_t);   // 33280
    size_t shm_kv = (size_t)(64 * 104 + 192 * 104) * sizeof(bf16_t);  // 53248
    k_proj_mfma<<<2400, 256, shm_q, stream>>>(xlnb, wqT, bq, 96, qb, nullptr);
    k_proj_mfma<<<2400, 256, shm_kv, stream>>>(ylnb, wkvT, bkv, 192, kb, vT);
    // xlnb/ylnb dead from here; aob reuses xlnb region, xc reuses ylnb region
    k_attn_mfma<<<2560, 256, 0, stream>>>(qb, kb, vT, wpjT, bias_mat, bpj, aob);
    k_mlp_mfma<<<1200, 256, 0, stream>>>(x2f, aob, g2, b2, w1T, b1, w2T, b2v, xc);
    k_conv<<<2400, 256, 0, stream>>>(xc, wcvT, zpad, cb, out);
}

// Round 15
// 480.323 us; speedup vs baseline: 1.0574x; 1.0574x over previous
//
#include <hip/hip_runtime.h>
#include <math.h>

// ---------------------------------------------------------------------------
// Swin-3D cross-attention block. Round 21: REVERT k_conv to v2 (verified
// R13 best, 485.2us total). R20's MFMA conv regressed 93.5->111.5us:
// VALU 68->5.8% (work removed as predicted) but MfmaUtil only 4.4% and
// VGPR=28 -> zero prefetch depth; 27 serial L2-latency taps per wave.
// MFMA-conv needs halo-staged LDS A-operands (new template, not a graft).
//  - k_ln v3 (vectorized h-pair), k_mlp v8 (LDS weight staging),
//    k_attn v2 (waveized, aob bf16 out), k_proj (LDS weights) retained.
// Token order = window-partitioned:
//   win = ((b*8 + d/5)*8 + h/6)*8 + w/5 ; t = ((d%5)*6 + h%6)*5 + w%5
// ---------------------------------------------------------------------------

static constexpr int NTOK = 153600;
static constexpr float SCALE = 0.10206207261596575f; // 96^-0.5

typedef __bf16 bf16_t;
typedef __bf16 bf16x8 __attribute__((ext_vector_type(8)));
typedef float f32x4 __attribute__((ext_vector_type(4)));

__device__ __forceinline__ int tok_index(int b, int d, int h, int w) {
    int d0 = d / 5, wd = d % 5;
    int h0 = h / 6, wh = h % 6;
    int w0 = w / 5, ww = w % 5;
    int win = ((b * 8 + d0) * 8 + h0) * 8 + w0;
    return win * 150 + (wd * 6 + wh) * 5 + ww;
}

__device__ __forceinline__ float gelu_f(float u) {
    float u2 = u * u;
    float arg = u * fmaf(0.0713549f, u2, 1.5957691f);
    float e = __expf(arg);
    float r = __builtin_amdgcn_rcpf(e + 1.f);
    return fmaf(-u, r, u);
}

// ---------------------------------------------------------------------------
// K0: weight convert/transpose bf16 [n][k]; fp32 bias matrix [160][160];
// conv weights re-laid to cwT[kk][oc][ci] (ci-contiguous for float4 reads).
// ---------------------------------------------------------------------------
__global__ __launch_bounds__(256) void k_prep_weights(
    const float* __restrict__ wq, const float* __restrict__ wkv,
    const float* __restrict__ w1, const float* __restrict__ w2,
    const float* __restrict__ wproj, const float* __restrict__ relb,
    const float* __restrict__ cw,
    bf16_t* wqT, bf16_t* wkvT, bf16_t* w1T, bf16_t* w2T, bf16_t* wpjT,
    float* bias_mat, float* cwT)
{
    int i = blockIdx.x * 256 + threadIdx.x;
    if (i < 9216)  wqT[i]  = (bf16_t)wq[(i % 96) * 96 + i / 96];
    if (i < 18432) wkvT[i] = (bf16_t)wkv[(i % 96) * 192 + i / 96];
    if (i < 36864) w1T[i]  = (bf16_t)w1[(i % 96) * 384 + i / 96];
    if (i < 36864) w2T[i]  = (bf16_t)w2[(i % 384) * 96 + i / 384];
    if (i < 9216)  wpjT[i] = (bf16_t)wproj[(i % 96) * 96 + i / 96];
    if (i < 25600) {
        int row = i / 160, col = i % 160;
        float v;
        if (col >= 150) v = -1e30f;
        else if (row >= 150) v = 0.f;
        else {
            int wd1 = row / 30, rh1 = row % 30, wh1 = rh1 / 5, ww1 = rh1 % 5;
            int wd2 = col / 30, rh2 = col % 30, wh2 = rh2 / 5, ww2 = rh2 % 5;
            int idx = (wd1 - wd2 + 4) * 99 + (wh1 - wh2 + 5) * 9 + (ww1 - ww2 + 4);
            v = relb[idx];
        }
        bias_mat[i] = v;
    }
    if (i < 7776) {
        int kk = i / 288, rem = i % 288;
        int oc = rem / 96, ci = rem % 96;
        cwT[i] = cw[oc * 2592 + ci * 27 + kk];
    }
}

// ---------------------------------------------------------------------------
// K1 v3: transpose->token order + LayerNorm + fp32 Im shortcut.
// One block per (b, d, h-pair): rows h0,h0+1 are CONTIGUOUS in memory ->
// float4 loads over 320B runs. Stores vectorized: bf16x8 (uint4) + 2x float4.
// grid = 1920, 256 threads, 2 passes (Im->xln/x2s, If->yln).
// ---------------------------------------------------------------------------
__global__ __launch_bounds__(256) void k_ln_transpose(
    const float* __restrict__ Im, const float* __restrict__ If,
    const float* __restrict__ g1q, const float* __restrict__ b1q,
    const float* __restrict__ g1k, const float* __restrict__ b1k,
    bf16_t* __restrict__ xln, bf16_t* __restrict__ yln,
    float* __restrict__ x2s)
{
    __shared__ float tile[80 * 97];          // 31040 B
    __shared__ float red_s[80][3], red2_s[80][3];
    __shared__ float mean_s[80], rstd_s[80];
    int blk = blockIdx.x;                    // 2 * 40 * 24
    int b = blk / (40 * 24);
    int rem = blk % (40 * 24);
    int d = rem / 24, hp = rem % 24;
    int h0 = hp * 2;
    int tid = threadIdx.x;

    for (int pass = 0; pass < 2; ++pass) {
        const float* src = pass ? If : Im;
        const float* gg = pass ? g1k : g1q;
        const float* bb = pass ? b1k : b1q;
        bf16_t* dst = pass ? yln : xln;

        // ---- load: float4 over the 80-float contiguous (h0,h0+1) span ----
        for (int i = tid; i < 1920; i += 256) {
            int c = i / 20, q = i % 20;
            float4 v = *(const float4*)(src + (size_t)(b * 96 + c) * 76800
                                        + d * 1920 + h0 * 40 + q * 4);
            int w0 = q * 4;
            tile[(w0 + 0) * 97 + c] = v.x;
            tile[(w0 + 1) * 97 + c] = v.y;
            tile[(w0 + 2) * 97 + c] = v.z;
            tile[(w0 + 3) * 97 + c] = v.w;
        }
        __syncthreads();
        // ---- stats: 240 threads, (token w6, third j) 32-chan partials ----
        if (tid < 240) {
            int w6 = tid / 3, j = tid % 3;
            const float* tp = tile + w6 * 97 + j * 32;
            float s = 0.f, s2 = 0.f;
#pragma unroll
            for (int c = 0; c < 32; ++c) { float v = tp[c]; s += v; s2 += v * v; }
            red_s[w6][j] = s;
            red2_s[w6][j] = s2;
        }
        __syncthreads();
        if (tid < 80) {
            float s = red_s[tid][0] + red_s[tid][1] + red_s[tid][2];
            float s2 = red2_s[tid][0] + red2_s[tid][1] + red2_s[tid][2];
            float m = s * (1.f / 96.f);
            float var = s2 * (1.f / 96.f) - m * m;
            mean_s[tid] = m;
            rstd_s[tid] = rsqrtf(var + 1e-5f);
        }
        __syncthreads();
        // ---- store: (token w, 8-chan group c8); vectorized 16B stores ----
        for (int i = tid; i < 960; i += 256) {
            int w = i / 12, c8 = i % 12;
            int hh = h0 + (w >= 40), ww = w - (w >= 40) * 40;
            int tok = tok_index(b, d, hh, ww);
            float m = mean_s[w], rs = rstd_s[w];
            const float4* ggv = (const float4*)(gg + c8 * 8);
            const float4* bbv = (const float4*)(bb + c8 * 8);
            float4 g0 = ggv[0], g1 = ggv[1];
            float4 b0 = bbv[0], b1v = bbv[1];
            const float* tp = tile + w * 97 + c8 * 8;
            float x0 = tp[0], x1 = tp[1], x2v = tp[2], x3 = tp[3];
            float x4 = tp[4], x5 = tp[5], x6 = tp[6], x7 = tp[7];
            bf16x8 tb;
            tb[0] = (bf16_t)((x0 - m) * rs * g0.x + b0.x);
            tb[1] = (bf16_t)((x1 - m) * rs * g0.y + b0.y);
            tb[2] = (bf16_t)((x2v - m) * rs * g0.z + b0.z);
            tb[3] = (bf16_t)((x3 - m) * rs * g0.w + b0.w);
            tb[4] = (bf16_t)((x4 - m) * rs * g1.x + b1v.x);
            tb[5] = (bf16_t)((x5 - m) * rs * g1.y + b1v.y);
            tb[6] = (bf16_t)((x6 - m) * rs * g1.z + b1v.z);
            tb[7] = (bf16_t)((x7 - m) * rs * g1.w + b1v.w);
            *(bf16x8*)(dst + (size_t)tok * 96 + c8 * 8) = tb;
            if (pass == 0) {
                float* xp = x2s + (size_t)tok * 96 + c8 * 8;
                *(float4*)(xp) = make_float4(x0, x1, x2v, x3);
                *(float4*)(xp + 4) = make_float4(x4, x5, x6, x7);
            }
        }
        __syncthreads();
    }
}

// ---------------------------------------------------------------------------
// K2: MFMA projection. WT is [N][96] bf16, staged once per block into LDS
// ([N][104] padded) so B-frags come from LDS, not per-MFMA global loads.
// N=96 -> qb only. N=192 -> n<96 writes kb [t][c]; n>=96 writes vT.
// grid = 2400 (64 tokens/block), 256 threads = 4 waves.
// dynamic LDS = (64*104 + N*104)*2 B.
// ---------------------------------------------------------------------------
__global__ __launch_bounds__(256) void k_proj_mfma(
    const bf16_t* __restrict__ X, const bf16_t* __restrict__ WT,
    const float* __restrict__ bias, int N,
    bf16_t* __restrict__ outA, bf16_t* __restrict__ vT)
{
    extern __shared__ bf16_t sm[];
    bf16_t* xs  = sm;             // [64][104]
    bf16_t* wsh = sm + 64 * 104;  // [N][104]
    int tid = threadIdx.x;
    int t0 = blockIdx.x * 64;

    const uint4* xg = (const uint4*)(X + (size_t)t0 * 96);
    uint4* xsv = (uint4*)xs;
    for (int i = tid; i < 768; i += 256) {
        int row = i / 12, c16 = i % 12;
        xsv[row * 13 + c16] = xg[i];
    }
    const uint4* wg = (const uint4*)WT;
    uint4* wsv = (uint4*)wsh;
    for (int i = tid; i < N * 12; i += 256) {
        int row = i / 12, c16 = i % 12;
        wsv[row * 13 + c16] = wg[i];
    }
    __syncthreads();

    int w = tid >> 6, l = tid & 63;
    int lm = l & 15, lk = (l >> 4) * 8;
    int m0 = w * 16;
    bf16x8 a[3];
#pragma unroll
    for (int kk = 0; kk < 3; ++kk)
        a[kk] = *(const bf16x8*)(xs + (m0 + lm) * 104 + kk * 32 + lk);

    int trow[4], twin[4], tm[4];
#pragma unroll
    for (int r = 0; r < 4; ++r) {
        int t = t0 + m0 + (l >> 4) * 4 + r;
        trow[r] = t; twin[r] = t / 150; tm[r] = t - twin[r] * 150;
    }

    int ntiles = N >> 4;
    for (int ti = 0; ti < ntiles; ++ti) {
        int n0 = ti * 16;
        f32x4 c = {0.f, 0.f, 0.f, 0.f};
        const bf16_t* wp = wsh + (size_t)(n0 + lm) * 104 + lk;
        c = __builtin_amdgcn_mfma_f32_16x16x32_bf16(a[0], *(const bf16x8*)(wp), c, 0, 0, 0);
        c = __builtin_amdgcn_mfma_f32_16x16x32_bf16(a[1], *(const bf16x8*)(wp + 32), c, 0, 0, 0);
        c = __builtin_amdgcn_mfma_f32_16x16x32_bf16(a[2], *(const bf16x8*)(wp + 64), c, 0, 0, 0);
        int n = n0 + lm;
        float bs = bias[n];
        if (n < 96) {
#pragma unroll
            for (int r = 0; r < 4; ++r)
                outA[(size_t)trow[r] * 96 + n] = (bf16_t)(c[r] + bs);
        } else {
            int cc = n - 96;
#pragma unroll
            for (int r = 0; r < 4; ++r)
                vT[((size_t)twin[r] * 96 + cc) * 160 + tm[r]] = (bf16_t)(c[r] + bs);
        }
    }
}

// ---------------------------------------------------------------------------
// K34 v2: waveized MFMA attention. One wave = one (window, row-tile) task,
// 10240 tasks, 4 waves/block, grid 2560. No barriers, no K staging (K is
// L1/L2-hot: 28.8 KB/window shared by its 10 waves). P/O transpose through
// wave-private LDS scratch [16][164]. K rows >=150 clamp-loaded (masked by
// bias -1e30). Output: aob[t][c] = O @ wprojT + bproj (bf16), no x2 RMW.
// ---------------------------------------------------------------------------
__global__ __launch_bounds__(256, 4) void k_attn_mfma(
    const bf16_t* __restrict__ qb, const bf16_t* __restrict__ kb,
    const bf16_t* __restrict__ vT, const bf16_t* __restrict__ wpjT,
    const float* __restrict__ bias_mat, const float* __restrict__ bproj,
    bf16_t* __restrict__ aob)
{
    __shared__ __align__(16) bf16_t pls_all[4 * 16 * 164]; // 20992 B
    int tid = threadIdx.x;
    int wv = tid >> 6, l = tid & 63;
    int task = blockIdx.x * 4 + wv;
    int win = task / 10, ti = task - win * 10;
    int lm = l & 15, lq = l >> 4, lk8 = lq * 8;
    size_t wbase = (size_t)win * 150 * 96;
    size_t vbase = (size_t)win * 96 * 160;
    bf16_t* pls = pls_all + wv * 16 * 164;
    int r0 = ti * 16;

    // ---- Q A-frags from global (rows >=150 read harmless garbage; masked) --
    bf16x8 aq[3];
#pragma unroll
    for (int kk = 0; kk < 3; ++kk)
        aq[kk] = *(const bf16x8*)(qb + wbase + (size_t)(r0 + lm) * 96 + kk * 32 + lk8);

    // ---- S = Q K^T (K B-frags from global, L1-hot; clamp rows >=150) ----
    f32x4 s[10];
#pragma unroll
    for (int nt = 0; nt < 10; ++nt) {
        int krow = nt * 16 + lm;
        if (krow > 149) krow = 149;   // finite duplicate, masked by bias
        f32x4 acc = {0.f, 0.f, 0.f, 0.f};
        const bf16_t* kp = kb + wbase + (size_t)krow * 96 + lk8;
        acc = __builtin_amdgcn_mfma_f32_16x16x32_bf16(aq[0], *(const bf16x8*)(kp), acc, 0, 0, 0);
        acc = __builtin_amdgcn_mfma_f32_16x16x32_bf16(aq[1], *(const bf16x8*)(kp + 32), acc, 0, 0, 0);
        acc = __builtin_amdgcn_mfma_f32_16x16x32_bf16(aq[2], *(const bf16x8*)(kp + 64), acc, 0, 0, 0);
        s[nt] = acc;
    }

    // ---- softmax (bias+mask folded into bias_mat) ----
#pragma unroll
    for (int r = 0; r < 4; ++r) {
        int grow = r0 + lq * 4 + r;
        float rowmax = -3.0e38f;
#pragma unroll
        for (int nt = 0; nt < 10; ++nt) {
            float bv = bias_mat[grow * 160 + nt * 16 + lm];
            float v = fmaf(s[nt][r], SCALE, bv);
            s[nt][r] = v;
            rowmax = fmaxf(rowmax, v);
        }
        rowmax = fmaxf(rowmax, __shfl_xor(rowmax, 1));
        rowmax = fmaxf(rowmax, __shfl_xor(rowmax, 2));
        rowmax = fmaxf(rowmax, __shfl_xor(rowmax, 4));
        rowmax = fmaxf(rowmax, __shfl_xor(rowmax, 8));
        float ssum = 0.f;
#pragma unroll
        for (int nt = 0; nt < 10; ++nt) {
            float e = __expf(s[nt][r] - rowmax);
            s[nt][r] = e;
            ssum += e;
        }
        ssum += __shfl_xor(ssum, 1);
        ssum += __shfl_xor(ssum, 2);
        ssum += __shfl_xor(ssum, 4);
        ssum += __shfl_xor(ssum, 8);
        float inv = 1.f / ssum;
        int lrow = lq * 4 + r;
#pragma unroll
        for (int nt = 0; nt < 10; ++nt)
            pls[lrow * 164 + nt * 16 + lm] = (bf16_t)(s[nt][r] * inv);
    }
    // wave-private LDS: no barrier needed (lgkmcnt orders within wave)

    // ---- O = P @ V (P A-frags from LDS, V B-frags from global, L2-hot) ----
    f32x4 o[6];
#pragma unroll
    for (int ct = 0; ct < 6; ++ct) o[ct] = (f32x4){0.f, 0.f, 0.f, 0.f};
#pragma unroll
    for (int kf = 0; kf < 5; ++kf) {
        bf16x8 ap = *(const bf16x8*)(pls + lm * 164 + kf * 32 + lk8);
#pragma unroll
        for (int ct = 0; ct < 6; ++ct) {
            const bf16_t* vp = vT + vbase + (size_t)(ct * 16 + lm) * 160 + kf * 32 + lk8;
            o[ct] = __builtin_amdgcn_mfma_f32_16x16x32_bf16(ap, *(const bf16x8*)(vp), o[ct], 0, 0, 0);
        }
    }

    // ---- O -> LDS (A-layout staging), reuse pls as [16][104] ----
#pragma unroll
    for (int ct = 0; ct < 6; ++ct)
#pragma unroll
        for (int r = 0; r < 4; ++r)
            pls[(lq * 4 + r) * 104 + ct * 16 + lm] = (bf16_t)o[ct][r];

    // ---- aob = O @ wprojT + bproj (bf16) ----
    bf16x8 ao[3];
#pragma unroll
    for (int kk = 0; kk < 3; ++kk)
        ao[kk] = *(const bf16x8*)(pls + lm * 104 + kk * 32 + lk8);
    f32x4 pj[6];
#pragma unroll
    for (int ct = 0; ct < 6; ++ct) {
        f32x4 acc = {0.f, 0.f, 0.f, 0.f};
        const bf16_t* wp = wpjT + (size_t)(ct * 16 + lm) * 96 + lk8;
        acc = __builtin_amdgcn_mfma_f32_16x16x32_bf16(ao[0], *(const bf16x8*)(wp), acc, 0, 0, 0);
        acc = __builtin_amdgcn_mfma_f32_16x16x32_bf16(ao[1], *(const bf16x8*)(wp + 32), acc, 0, 0, 0);
        acc = __builtin_amdgcn_mfma_f32_16x16x32_bf16(ao[2], *(const bf16x8*)(wp + 64), acc, 0, 0, 0);
        pj[ct] = acc;
    }
#pragma unroll
    for (int r = 0; r < 4; ++r) {
        int gr = r0 + lq * 4 + r;
        if (gr < 150) {
            size_t t = (size_t)win * 150 + gr;
#pragma unroll
            for (int ct = 0; ct < 6; ++ct) {
                int c = ct * 16 + lm;
                aob[t * 96 + c] = (bf16_t)(pj[ct][r] + bproj[c]);
            }
        }
    }
}

// ---------------------------------------------------------------------------
// K5: MFMA MLP v8. Weight chunks staged cooperatively in LDS (k_proj
// pattern). xs/h alias retained (wave-private). LDS 46592 B -> 3 blk/CU.
// grid = 1200 (128 tokens), 256 threads = 4 waves, 32 tokens/wave.
// ---------------------------------------------------------------------------
__global__ __launch_bounds__(256, 3) void k_mlp_mfma(
    const float* __restrict__ x2,
    const bf16_t* __restrict__ aob,
    const float* __restrict__ g2, const float* __restrict__ b2,
    const bf16_t* __restrict__ w1T, const float* __restrict__ b1,
    const bf16_t* __restrict__ w2T, const float* __restrict__ b2v,
    bf16_t* __restrict__ xc)
{
    __shared__ __align__(16) bf16_t xs[128 * 104];   // 26624 B (xs, then h)
    __shared__ __align__(16) bf16_t wsm[96 * 104];   // 19968 B (weight chunk)

    int tid = threadIdx.x;
    int t0 = blockIdx.x * 128;

    // ---- register LayerNorm: thread = (token t, half p); x2 = x2s + aob ----
    {
        int t = tid >> 1, p = tid & 1;
        float xr[48];
        const float4* xg = (const float4*)(x2 + (size_t)(t0 + t) * 96 + p * 48);
        const bf16x8* ag = (const bf16x8*)(aob + (size_t)(t0 + t) * 96 + p * 48);
#pragma unroll
        for (int j4 = 0; j4 < 12; ++j4) {
            float4 v = xg[j4];
            xr[j4 * 4 + 0] = v.x; xr[j4 * 4 + 1] = v.y;
            xr[j4 * 4 + 2] = v.z; xr[j4 * 4 + 3] = v.w;
        }
#pragma unroll
        for (int j8 = 0; j8 < 6; ++j8) {
            bf16x8 av = ag[j8];
#pragma unroll
            for (int e = 0; e < 8; ++e)
                xr[j8 * 8 + e] += (float)av[e];
        }
        float s = 0.f, s2 = 0.f;
#pragma unroll
        for (int j = 0; j < 48; ++j) { s += xr[j]; s2 += xr[j] * xr[j]; }
        s += __shfl_xor(s, 1);
        s2 += __shfl_xor(s2, 1);
        float m = s * (1.f / 96.f);
        float var = s2 * (1.f / 96.f) - m * m;
        float rstd = rsqrtf(var + 1e-5f);

        const float4* gg = (const float4*)(g2 + p * 48);
        const float4* bb = (const float4*)(b2 + p * 48);
        bf16_t tmp[48];
#pragma unroll
        for (int j4 = 0; j4 < 12; ++j4) {
            float4 g = gg[j4], bv = bb[j4];
            tmp[j4 * 4 + 0] = (bf16_t)((xr[j4 * 4 + 0] - m) * rstd * g.x + bv.x);
            tmp[j4 * 4 + 1] = (bf16_t)((xr[j4 * 4 + 1] - m) * rstd * g.y + bv.y);
            tmp[j4 * 4 + 2] = (bf16_t)((xr[j4 * 4 + 2] - m) * rstd * g.z + bv.z);
            tmp[j4 * 4 + 3] = (bf16_t)((xr[j4 * 4 + 3] - m) * rstd * g.w + bv.w);
        }
        uint4* dst = (uint4*)(xs + t * 104 + p * 48);   // 96B per half
        const uint4* src = (const uint4*)tmp;
#pragma unroll
        for (int j = 0; j < 6; ++j) dst[j] = src[j];
    }
    // NO barrier for xs: token rows [32w,32w+32) are written by wave w's own
    // tids; in-wave DS ordering suffices. Barriers below only guard wsm.

    int w = tid >> 6, l = tid & 63;
    int lm = l & 15, lq = l >> 4, lk = lq * 8;
    int m0 = w * 32;
    bf16_t* hw = xs + w * 32 * 104;   // ALIAS: xs rows dead after a-frag load

    bf16x8 a[2][3];
#pragma unroll
    for (int mt = 0; mt < 2; ++mt)
#pragma unroll
        for (int kk = 0; kk < 3; ++kk)
            a[mt][kk] = *(const bf16x8*)(xs + (m0 + mt * 16 + lm) * 104 + kk * 32 + lk);

    f32x4 acc2[2][6];
#pragma unroll
    for (int mt = 0; mt < 2; ++mt)
#pragma unroll
        for (int i = 0; i < 6; ++i) acc2[mt][i] = (f32x4){0.f, 0.f, 0.f, 0.f};

    // cooperative stage of a [96][96] weight chunk into wsm[96][104]
    auto stage_w = [&](const bf16_t* src, int srcStride) {
        uint4* wv = (uint4*)wsm;
        for (int i = tid; i < 1152; i += 256) {
            int row = i / 12, c = i - row * 12;
            wv[row * 13 + c] = *(const uint4*)(src + (size_t)row * srcStride + c * 8);
        }
    };

#pragma unroll
    for (int cc = 0; cc < 4; ++cc) {
        // ---- stage w1 chunk; all waves consume from LDS ----
        stage_w(w1T + (size_t)cc * 96 * 96, 96);
        __syncthreads();
        // ---- stage1: h = gelu(x @ w1_cc + b1) ----
#pragma unroll
        for (int ti = 0; ti < 6; ++ti) {
            int n = cc * 96 + ti * 16 + lm;
            const bf16_t* wp = wsm + (size_t)(ti * 16 + lm) * 104 + lk;
            bf16x8 w0 = *(const bf16x8*)(wp);
            bf16x8 w1v = *(const bf16x8*)(wp + 32);
            bf16x8 w2v = *(const bf16x8*)(wp + 64);
            float bs = b1[n];
#pragma unroll
            for (int mt = 0; mt < 2; ++mt) {
                f32x4 c1 = {0.f, 0.f, 0.f, 0.f};
                c1 = __builtin_amdgcn_mfma_f32_16x16x32_bf16(a[mt][0], w0, c1, 0, 0, 0);
                c1 = __builtin_amdgcn_mfma_f32_16x16x32_bf16(a[mt][1], w1v, c1, 0, 0, 0);
                c1 = __builtin_amdgcn_mfma_f32_16x16x32_bf16(a[mt][2], w2v, c1, 0, 0, 0);
#pragma unroll
                for (int r = 0; r < 4; ++r)
                    hw[(mt * 16 + lq * 4 + r) * 104 + ti * 16 + lm] =
                        (bf16_t)gelu_f(c1[r] + bs);
            }
        }
        __syncthreads();   // all wsm (w1) reads done before overwrite

        // ---- stage w2 chunk; consume from LDS ----
        stage_w(w2T + (size_t)cc * 96, 384);
        __syncthreads();
        // ---- stage2: acc2 += h_cc @ w2_cc ----
        bf16x8 ha[2][3];
#pragma unroll
        for (int mt = 0; mt < 2; ++mt)
#pragma unroll
            for (int kk = 0; kk < 3; ++kk)
                ha[mt][kk] = *(const bf16x8*)(hw + (mt * 16 + lm) * 104 + kk * 32 + lk);
#pragma unroll
        for (int ti = 0; ti < 6; ++ti) {
            const bf16_t* wp = wsm + (size_t)(ti * 16 + lm) * 104 + lk;
            bf16x8 v0 = *(const bf16x8*)(wp);
            bf16x8 v1 = *(const bf16x8*)(wp + 32);
            bf16x8 v2 = *(const bf16x8*)(wp + 64);
#pragma unroll
            for (int mt = 0; mt < 2; ++mt) {
                acc2[mt][ti] = __builtin_amdgcn_mfma_f32_16x16x32_bf16(ha[mt][0], v0, acc2[mt][ti], 0, 0, 0);
                acc2[mt][ti] = __builtin_amdgcn_mfma_f32_16x16x32_bf16(ha[mt][1], v1, acc2[mt][ti], 0, 0, 0);
                acc2[mt][ti] = __builtin_amdgcn_mfma_f32_16x16x32_bf16(ha[mt][2], v2, acc2[mt][ti], 0, 0, 0);
            }
        }
        if (cc < 3) __syncthreads();   // wsm (w2) reads done before next cc
    }

    // epilogue: residual (x2s + aob) + bias; write bf16 in spatial order
#pragma unroll
    for (int mt = 0; mt < 2; ++mt) {
        int srow[4];
#pragma unroll
        for (int r = 0; r < 4; ++r) {
            int t = t0 + m0 + mt * 16 + lq * 4 + r;
            int win = t / 150, nn = t - win * 150;
            int b = win >> 9, d0 = (win >> 6) & 7, h0 = (win >> 3) & 7, w0 = win & 7;
            int wd = nn / 30, rem = nn % 30, wh = rem / 5, ww = rem % 5;
            srow[r] = ((b * 40 + d0 * 5 + wd) * 48 + h0 * 6 + wh) * 40 + w0 * 5 + ww;
        }
#pragma unroll
        for (int ti = 0; ti < 6; ++ti) {
            int n = ti * 16 + lm;
            float bs = b2v[n];
#pragma unroll
            for (int r = 0; r < 4; ++r) {
                int t = t0 + m0 + mt * 16 + lq * 4 + r;
                size_t o = (size_t)t * 96 + n;
                float base = x2[o] + (float)aob[o];
                xc[(size_t)srow[r] * 96 + n] = (bf16_t)(base + acc2[mt][ti][r] + bs);
            }
        }
    }
}

// ---------------------------------------------------------------------------
// K6: 3x3x3 conv (96 -> 3), zero pad. Input xc: bf16, spatial (b,d,h,w,c).
// v2: 4 lanes per point, 24 ci each (3 bf16x8 chunks); shfl_xor reduce over
// lanes 1,2; lane p<3 writes output plane p. grid = 2400.
// ---------------------------------------------------------------------------
__global__ __launch_bounds__(256) void k_conv(
    const bf16_t* __restrict__ xc, const float* __restrict__ cwT,
    const float* __restrict__ cb, float* __restrict__ out)
{
    __shared__ float wl[7776];   // [kk][oc][ci]
    int tid = threadIdx.x;
    for (int i = tid; i < 7776; i += 256) wl[i] = cwT[i];
    __syncthreads();

    int gid = blockIdx.x * 256 + tid;
    int s = gid >> 2, p = gid & 3;          // point, ci-quarter
    int b = s / 76800, r = s % 76800;
    int d = r / 1920, h = (r / 40) % 48, w = r % 40;
    float a0 = 0.f, a1 = 0.f, a2 = 0.f;

    for (int dd = 0; dd < 3; ++dd) {
        int d2 = d + dd - 1;
        if ((unsigned)d2 >= 40u) continue;
        for (int hh = 0; hh < 3; ++hh) {
            int h2 = h + hh - 1;
            if ((unsigned)h2 >= 48u) continue;
            for (int ww = 0; ww < 3; ++ww) {
                int w2 = w + ww - 1;
                if ((unsigned)w2 >= 40u) continue;
                int kk = (dd * 3 + hh) * 3 + ww;
                const bf16x8* xp = (const bf16x8*)
                    (xc + ((size_t)((b * 40 + d2) * 48 + h2) * 40 + w2) * 96 + p * 24);
                const float* wk = wl + kk * 288 + p * 24;
#pragma unroll
                for (int c8 = 0; c8 < 3; ++c8) {
                    bf16x8 xv = xp[c8];
                    float x0 = (float)xv[0], x1 = (float)xv[1];
                    float x2v = (float)xv[2], x3 = (float)xv[3];
                    float x4 = (float)xv[4], x5 = (float)xv[5];
                    float x6 = (float)xv[6], x7 = (float)xv[7];
                    float4 wa0 = *(const float4*)(wk + c8 * 8);
                    float4 wb0 = *(const float4*)(wk + c8 * 8 + 4);
                    float4 wa1 = *(const float4*)(wk + 96 + c8 * 8);
                    float4 wb1 = *(const float4*)(wk + 96 + c8 * 8 + 4);
                    float4 wa2 = *(const float4*)(wk + 192 + c8 * 8);
                    float4 wb2 = *(const float4*)(wk + 192 + c8 * 8 + 4);
                    a0 += x0 * wa0.x + x1 * wa0.y + x2v * wa0.z + x3 * wa0.w
                        + x4 * wb0.x + x5 * wb0.y + x6 * wb0.z + x7 * wb0.w;
                    a1 += x0 * wa1.x + x1 * wa1.y + x2v * wa1.z + x3 * wa1.w
                        + x4 * wb1.x + x5 * wb1.y + x6 * wb1.z + x7 * wb1.w;
                    a2 += x0 * wa2.x + x1 * wa2.y + x2v * wa2.z + x3 * wa2.w
                        + x4 * wb2.x + x5 * wb2.y + x6 * wb2.z + x7 * wb2.w;
                }
            }
        }
    }
    // reduce over the 4 ci-quarters (lanes p^1, p^2)
    a0 += __shfl_xor(a0, 1); a0 += __shfl_xor(a0, 2);
    a1 += __shfl_xor(a1, 1); a1 += __shfl_xor(a1, 2);
    a2 += __shfl_xor(a2, 1); a2 += __shfl_xor(a2, 2);
    float av = (p == 0) ? a0 : ((p == 1) ? a1 : a2);
    if (p < 3)
        out[(size_t)(b * 3 + p) * 76800 + r] = av + cb[p];
}

// ---------------------------------------------------------------------------
extern "C" void kernel_launch(void* const* d_in, const int* in_sizes, int n_in,
                              void* d_out, int out_size, void* d_ws, size_t ws_size,
                              hipStream_t stream)
{
    (void)in_sizes; (void)n_in; (void)out_size;

    const float* Im  = (const float*)d_in[0];
    const float* If  = (const float*)d_in[1];
    const float* g1q = (const float*)d_in[2];
    const float* b1q = (const float*)d_in[3];
    const float* g1k = (const float*)d_in[4];
    const float* b1k = (const float*)d_in[5];
    const float* wq  = (const float*)d_in[6];
    const float* bq  = (const float*)d_in[7];
    const float* wkv = (const float*)d_in[8];
    const float* bkv = (const float*)d_in[9];
    const float* wpj = (const float*)d_in[10];
    const float* bpj = (const float*)d_in[11];
    const float* rb  = (const float*)d_in[12];
    const float* g2  = (const float*)d_in[13];
    const float* b2  = (const float*)d_in[14];
    const float* w1  = (const float*)d_in[15];
    const float* b1  = (const float*)d_in[16];
    const float* w2  = (const float*)d_in[17];
    const float* b2v = (const float*)d_in[18];
    const float* cw  = (const float*)d_in[19];
    const float* cb  = (const float*)d_in[20];
    float* out = (float*)d_out;

    size_t U = (size_t)NTOK * 96;
    if (ws_size < 4 * U * sizeof(float)) return;
    float* ws = (float*)d_ws;
    bf16_t* xlnb = (bf16_t*)ws;                        // U bf16 (-> aob later)
    bf16_t* ylnb = (bf16_t*)(ws + U / 2);              // U bf16 (-> xc later)
    bf16_t* qb   = (bf16_t*)(ws + U);                  // U bf16
    bf16_t* kb   = (bf16_t*)(ws + 3 * U / 2);          // U bf16
    bf16_t* vT   = (bf16_t*)(ws + 2 * U);              // 1024*96*160 bf16
    float*  wtail = ws + 2 * U + (1024 * 96 * 160) / 2;
    bf16_t* wqT  = (bf16_t*)wtail;                     // 9216
    bf16_t* wkvT = wqT + 9216;                         // 18432
    bf16_t* w1T  = wkvT + 18432;                       // 36864
    bf16_t* w2T  = w1T + 36864;                        // 36864
    bf16_t* wpjT = w2T + 36864;                        // 9216
    float*  bias_mat = (float*)(wpjT + 9216 + 2);      // 25600 fp32
    float*  cwT  = bias_mat + 25600;                   // 7776 fp32
    float*  x2f  = ws + 3 * U;                         // U fp32 (x2s shortcut)
    bf16_t* aob  = (bf16_t*)ws;                        // U bf16 (attn out)
    bf16_t* xc   = (bf16_t*)(ws + U / 2);              // U bf16, spatial order

    k_prep_weights<<<144, 256, 0, stream>>>(wq, wkv, w1, w2, wpj, rb, cw,
                                            wqT, wkvT, w1T, w2T, wpjT,
                                            bias_mat, cwT);
    k_ln_transpose<<<1920, 256, 0, stream>>>(Im, If, g1q, b1q, g1k, b1k,
                                             xlnb, ylnb, x2f);
    size_t shm_q  = (size_t)(64 * 104 + 96 * 104) * sizeof(bf16_t);   // 33280
    size_t shm_kv = (size_t)(64 * 104 + 192 * 104) * sizeof(bf16_t);  // 53248
    k_proj_mfma<<<2400, 256, shm_q, stream>>>(xlnb, wqT, bq, 96, qb, nullptr);
    k_proj_mfma<<<2400, 256, shm_kv, stream>>>(ylnb, wkvT, bkv, 192, kb, vT);
    // xlnb/ylnb dead from here; aob reuses xlnb region, xc reuses ylnb region
    k_attn_mfma<<<2560, 256, 0, stream>>>(qb, kb, vT, wpjT, bias_mat, bpj, aob);
    k_mlp_mfma<<<1200, 256, 0, stream>>>(x2f, aob, g2, b2, w1T, b1, w2T, b2v, xc);
    k_conv<<<2400, 256, 0, stream>>>(xc, cwT, cb, out);
}